// Round 21
// baseline (190.526 us; speedup 1.0000x reference)
//
#include <hip/hip_runtime.h>
#include <hip/hip_bf16.h>
#include <math.h>

#define B_  4
#define T_  2048
#define D_  1024
#define H_  16
#define HD_ 64
#define M_  8192   // B_*T_

typedef __attribute__((ext_vector_type(8))) _Float16 f16x8;
typedef __attribute__((ext_vector_type(2))) __fp16  h16x2;
typedef __attribute__((ext_vector_type(4))) float   f32x4;

static __device__ __forceinline__ unsigned short f2h(float f){
    union { _Float16 h; unsigned short u; } cv; cv.h = (_Float16)f; return cv.u;
}
static __device__ __forceinline__ unsigned int pkh2(float a, float b){
    union { h16x2 h; unsigned int u; } cv;
    cv.h = __builtin_amdgcn_cvt_pkrtz(a, b);
    return cv.u;
}
static __device__ __forceinline__ void gload_lds16(const void* g, void* l){
    __builtin_amdgcn_global_load_lds(
        (const __attribute__((address_space(1))) unsigned int*)g,
        (__attribute__((address_space(3))) unsigned int*)l, 16, 0, 0);
}

union U16x16 { unsigned short us[16]; uint4 q[2]; };
union U16x4  { unsigned short us[4];  uint2 q;    };

// ---------------------------------------------------------------------------
// prep_xh: x fp32 [8192][1024] -> xb fp16. 16 el/thread.
// ---------------------------------------------------------------------------
__global__ __launch_bounds__(256) void prep_xh(
    const float* __restrict__ x, unsigned short* __restrict__ xb)
{
    const size_t i = ((size_t)blockIdx.x*256 + threadIdx.x)*16;
    U16x16 u;
#pragma unroll
    for (int j=0;j<16;j+=4){
        float4 f = *(const float4*)(x+i+j);
        u.us[j+0]=f2h(f.x); u.us[j+1]=f2h(f.y);
        u.us[j+2]=f2h(f.z); u.us[j+3]=f2h(f.w);
    }
    *(uint4*)(xb+i)   = u.q[0];
    *(uint4*)(xb+i+8) = u.q[1];
}

// ---------------------------------------------------------------------------
// prep_wqkvh: W{q,k,v}[16][1024][64] -> wt[3072][1024] fp16 (operand-major).
// ---------------------------------------------------------------------------
__global__ __launch_bounds__(256) void prep_wqkvh(
    const float* __restrict__ Wq, const float* __restrict__ Wk,
    const float* __restrict__ Wv, unsigned short* __restrict__ wt)
{
    const int dt = blockIdx.x;
    const int zh = blockIdx.y;
    const int z = zh >> 4, h = zh & 15;
    const float* src = ((z==0)?Wq:(z==1)?Wk:Wv) + (size_t)h*1024*64;
    __shared__ float Tt[64][68];
    const int t = threadIdx.x;
    const int r = t >> 2, c4 = (t & 3) * 16;
    const float* sp = src + (size_t)(dt*64 + r)*64 + c4;
    float4 v0=*(const float4*)(sp+0), v1=*(const float4*)(sp+4);
    float4 v2=*(const float4*)(sp+8), v3=*(const float4*)(sp+12);
    *(float4*)&Tt[r][c4+ 0]=v0; *(float4*)&Tt[r][c4+ 4]=v1;
    *(float4*)&Tt[r][c4+ 8]=v2; *(float4*)&Tt[r][c4+12]=v3;
    __syncthreads();
    const int er = t >> 2, dk = (t & 3) * 16;
    U16x16 u;
#pragma unroll
    for (int j=0;j<16;j++) u.us[j] = f2h(Tt[dk+j][er]);
    unsigned short* dst = wt + (size_t)(z*1024 + h*64 + er)*1024 + dt*64 + dk;
    *(uint4*)(dst)   = u.q[0];
    *(uint4*)(dst+8) = u.q[1];
}

// ---------------------------------------------------------------------------
// prep_woh: Wo[1024][1024] -> wot[n][k] fp16.
// ---------------------------------------------------------------------------
__global__ __launch_bounds__(256) void prep_woh(
    const float* __restrict__ Wo, unsigned short* __restrict__ wot)
{
    const int kt = blockIdx.x, nt = blockIdx.y;
    __shared__ float Tt[64][68];
    const int t = threadIdx.x;
    const int r = t >> 2, c4 = (t & 3) * 16;
    const float* sp = Wo + (size_t)(kt*64 + r)*1024 + nt*64 + c4;
    float4 v0=*(const float4*)(sp+0), v1=*(const float4*)(sp+4);
    float4 v2=*(const float4*)(sp+8), v3=*(const float4*)(sp+12);
    *(float4*)&Tt[r][c4+ 0]=v0; *(float4*)&Tt[r][c4+ 4]=v1;
    *(float4*)&Tt[r][c4+ 8]=v2; *(float4*)&Tt[r][c4+12]=v3;
    __syncthreads();
    const int er = t >> 2, dk = (t & 3) * 16;
    U16x16 u;
#pragma unroll
    for (int j=0;j<16;j++) u.us[j] = f2h(Tt[dk+j][er]);
    unsigned short* dst = wot + (size_t)(nt*64 + er)*1024 + kt*64 + dk;
    *(uint4*)(dst)   = u.q[0];
    *(uint4*)(dst+8) = u.q[1];
}

// ---------------------------------------------------------------------------
// gemm_qkvh: unchanged (q scale folds 8*log2(e)).
// ---------------------------------------------------------------------------
__global__ __launch_bounds__(256) void gemm_qkvh(
    const unsigned short* __restrict__ xb, const unsigned short* __restrict__ wt,
    const float* __restrict__ bqv, const float* __restrict__ bkv,
    const float* __restrict__ bvv,
    unsigned short* __restrict__ qp, unsigned short* __restrict__ kp,
    unsigned short* __restrict__ vtp)
{
    const int m0 = blockIdx.x * 128;
    const int n0 = blockIdx.y * 128;
    const int tid = threadIdx.x;
    const int lane = tid & 63, w = tid >> 6;
    const int wr = w >> 1, wc = w & 1;
    const int fla = lane & 15, flb = lane >> 4;

    __shared__ unsigned short As[128*32];
    __shared__ unsigned short Bs[128*32];

    f32x4 acc[4][4];
#pragma unroll
    for (int i=0;i<4;i++)
#pragma unroll
        for (int j=0;j<4;j++) acc[i][j] = (f32x4){0.f,0.f,0.f,0.f};

    const int srow0 = w*32 + (lane>>2);
    const int srow1 = srow0 + 16;
    const int spc   = lane & 3;
    const size_t ga0 = (size_t)(m0+srow0)*1024 + (size_t)((spc ^ ((srow0>>1)&3))*8);
    const size_t ga1 = (size_t)(m0+srow1)*1024 + (size_t)((spc ^ ((srow1>>1)&3))*8);
    const size_t gb0 = (size_t)(n0+srow0)*1024 + (size_t)((spc ^ ((srow0>>1)&3))*8);
    const size_t gb1 = (size_t)(n0+srow1)*1024 + (size_t)((spc ^ ((srow1>>1)&3))*8);
    const int ldso0 = w*1024;          // shorts
    const int ldso1 = w*1024 + 512;
    const int pchunk = (flb ^ ((fla>>1)&3)) * 8;

    for (int ks = 0; ks < 32; ++ks){
        const size_t k0 = (size_t)ks*32;
        __syncthreads();   // prev chunk's fragment reads complete
        gload_lds16(xb + ga0 + k0, As + ldso0);
        gload_lds16(xb + ga1 + k0, As + ldso1);
        gload_lds16(wt + gb0 + k0, Bs + ldso0);
        gload_lds16(wt + gb1 + k0, Bs + ldso1);
        __syncthreads();   // vmcnt(0) drained at barrier

        f16x8 af[4], bfr[4];
#pragma unroll
        for (int mf=0; mf<4; ++mf)
            af[mf] = *(const f16x8*)&As[(wr*64+mf*16+fla)*32 + pchunk];
#pragma unroll
        for (int nf=0; nf<4; ++nf)
            bfr[nf] = *(const f16x8*)&Bs[(wc*64+nf*16+fla)*32 + pchunk];
#pragma unroll
        for (int mf=0; mf<4; ++mf)
#pragma unroll
            for (int nf=0; nf<4; ++nf)
                acc[mf][nf] = __builtin_amdgcn_mfma_f32_16x16x32_f16(
                                  af[mf], bfr[nf], acc[mf][nf], 0, 0, 0);
    }

#pragma unroll
    for (int nf=0; nf<4; ++nf){
        const int c = n0 + wc*64 + nf*16 + fla;
        const int z = c >> 10, rem = c & 1023;
        const int h = rem >> 6, e = rem & 63;
        if (z < 2){
            const float bias = ((z==0)?bqv:bkv)[rem];
            const float scl  = (z==0) ? 11.541560327111708f   // 8*log2(e)
                                      : 1.0f;
            unsigned short* op = (z==0)?qp:kp;
#pragma unroll
            for (int mf=0; mf<4; ++mf){
#pragma unroll
                for (int ri=0; ri<4; ++ri){
                    const int m = m0 + wr*64 + mf*16 + flb*4 + ri;
                    const int b = m >> 11, t = m & (T_-1);
                    op[((size_t)(b*H_ + h)*T_ + t)*HD_ + e] =
                        f2h((acc[mf][nf][ri] + bias) * scl);
                }
            }
        } else {
            const float bias = bvv[rem];
#pragma unroll
            for (int mf=0; mf<4; ++mf){
                const int m = m0 + wr*64 + mf*16 + flb*4;   // 4 consecutive t
                const int b = m >> 11, t = m & (T_-1);
                U16x4 u;
#pragma unroll
                for (int ri=0; ri<4; ++ri)
                    u.us[ri] = f2h(acc[mf][nf][ri] + bias);
                *(uint2*)(vtp + ((size_t)(b*H_ + h)*HD_ + e)*T_ + t) = u.q;
            }
        }
    }
}

// ---------------------------------------------------------------------------
// gemm_o: out = att(fp16) @ wot(fp16) + bo. (unchanged)
// ---------------------------------------------------------------------------
__global__ __launch_bounds__(256) void gemm_o(
    const unsigned short* __restrict__ attb, const unsigned short* __restrict__ wot,
    const float* __restrict__ bo, float* __restrict__ out)
{
    const int m0 = blockIdx.x * 128;
    const int n0 = blockIdx.y * 128;
    const int tid = threadIdx.x;
    const int lane = tid & 63, w = tid >> 6;
    const int wr = w >> 1, wc = w & 1;
    const int fla = lane & 15, flb = lane >> 4;

    __shared__ unsigned short As[4096];
    __shared__ unsigned short Bs[4096];

    f32x4 acc[4][4];
#pragma unroll
    for (int i=0;i<4;i++)
#pragma unroll
        for (int j=0;j<4;j++) acc[i][j] = (f32x4){0.f,0.f,0.f,0.f};

    const int srow0 = w*32 + (lane>>2);
    const int srow1 = srow0 + 16;
    const int spc   = lane & 3;
    const size_t ga0 = (size_t)(m0+srow0)*1024 + (size_t)((spc ^ ((srow0>>1)&3))*8);
    const size_t ga1 = (size_t)(m0+srow1)*1024 + (size_t)((spc ^ ((srow1>>1)&3))*8);
    const size_t gb0 = (size_t)(n0+srow0)*1024 + (size_t)((spc ^ ((srow0>>1)&3))*8);
    const size_t gb1 = (size_t)(n0+srow1)*1024 + (size_t)((spc ^ ((srow1>>1)&3))*8);
    const int ldso0 = w*1024;
    const int ldso1 = w*1024 + 512;
    const int pchunk = (flb ^ ((fla>>1)&3)) * 8;

    for (int ks = 0; ks < 32; ++ks){
        const size_t k0 = (size_t)ks*32;
        __syncthreads();
        gload_lds16(attb + ga0 + k0, As + ldso0);
        gload_lds16(attb + ga1 + k0, As + ldso1);
        gload_lds16(wot  + gb0 + k0, Bs + ldso0);
        gload_lds16(wot  + gb1 + k0, Bs + ldso1);
        __syncthreads();

        f16x8 af[4], bfr[4];
#pragma unroll
        for (int mf=0; mf<4; ++mf)
            af[mf] = *(const f16x8*)&As[(wr*64+mf*16+fla)*32 + pchunk];
#pragma unroll
        for (int nf=0; nf<4; ++nf)
            bfr[nf] = *(const f16x8*)&Bs[(wc*64+nf*16+fla)*32 + pchunk];
#pragma unroll
        for (int mf=0; mf<4; ++mf)
#pragma unroll
            for (int nf=0; nf<4; ++nf)
                acc[mf][nf] = __builtin_amdgcn_mfma_f32_16x16x32_f16(
                                  af[mf], bfr[nf], acc[mf][nf], 0, 0, 0);
    }

#pragma unroll
    for (int nf=0; nf<4; ++nf){
        const int n = n0 + wc*64 + nf*16 + fla;
        const float bias = bo[n];
#pragma unroll
        for (int mf=0; mf<4; ++mf){
#pragma unroll
            for (int ri=0; ri<4; ++ri){
                const int m = m0 + wr*64 + mf*16 + flb*4 + ri;
                out[(size_t)m*D_ + n] = acc[mf][nf][ri] + bias;
            }
        }
    }
}

// ---------------------------------------------------------------------------
// MFMA flash attention, fp16, exp2-domain, KVBLK=128, swapped QK^T,
// KS/PsS LDS OVERLAY: K tile dead after QK^T -> P tile reuses its 16KB.
// LDS 32KB total -> 5 blocks/CU. 3 barriers per 128-key chunk (the third
// guards K-read -> P-overwrite). PV's PsS rows remain wave-private.
// ---------------------------------------------------------------------------
__global__ __launch_bounds__(256) void attn_mfma(
    const unsigned short* __restrict__ qp, const unsigned short* __restrict__ kp,
    const unsigned short* __restrict__ vtp, unsigned short* __restrict__ attb,
    const int* __restrict__ maskp)
{
    const int bid = blockIdx.x;
    const int qb  = 31 - (bid >> 6);   // big blocks first
    const int bh  = bid & 63;
    const int b   = bh >> 4, h = bh & 15;
    const int tid = threadIdx.x;
    const int lane = tid & 63, w = tid >> 6;
    const int l16 = lane & 15, h16 = lane >> 4;
    const int domask = maskp[0];

    __shared__ unsigned short KPS[8192];         // K tile, then P tile (16KB)
    __shared__ unsigned short VtS[4][64][32];    // [key-chunk][d][key%32]

    const int qrow = qb*64 + w*16 + l16;         // this lane's softmax row
    const size_t qoff = ((size_t)bh*T_ + qrow)*HD_ + 8*h16;
    const f16x8 q0 = *(const f16x8*)(qp + qoff);
    const f16x8 q1 = *(const f16x8*)(qp + qoff + 32);

    f32x4 accO[4];
#pragma unroll
    for (int j=0;j<4;j++) accO[j] = (f32x4){0.f,0.f,0.f,0.f};
    float m_run = -INFINITY, lpart = 0.f;

    // staging geometry
    const int kr = tid >> 1;          // 0..127 key row (K)
    const int kh = tid & 1;           // d-half (K)
    const int fk = (kr >> 1) & 3;
    const int vr = tid >> 2;          // 0..63 d row (V)
    const int vq = tid & 3;           // key quarter (V)
    const int fv = (vr >> 1) & 3;

    // fragment-read swizzle (all fragment rows == l16 mod 16)
    const int off = (h16 ^ ((l16>>1)&3)) * 8;
    const int psw = (l16>>1)&3;       // P-row swizzle key (row = w*16+l16)

    const size_t kbase = (size_t)bh*T_*HD_;
    const size_t vbase = (size_t)bh*HD_*T_;

    const int nchunks = domask ? ((qb+2)>>1) : 16;   // ceil((qb+1)/2)
    for (int ci = 0; ci < nchunks; ++ci){
        const int kb = ci << 7;
        const unsigned short* ksrc = kp + kbase + (size_t)(kb+kr)*HD_ + kh*32;
        uint4 ka0=*(const uint4*)(ksrc),    ka1=*(const uint4*)(ksrc+8);
        uint4 ka2=*(const uint4*)(ksrc+16), ka3=*(const uint4*)(ksrc+24);
        const unsigned short* vsrc = vtp + vbase + (size_t)vr*T_ + kb + vq*32;
        uint4 va0=*(const uint4*)(vsrc),    va1=*(const uint4*)(vsrc+8);
        uint4 va2=*(const uint4*)(vsrc+16), va3=*(const uint4*)(vsrc+24);
        __syncthreads();   // prev chunk's PV reads (KPS=P rows, VtS) complete
        *(uint4*)&KPS[kh*4096 + kr*32 + ((0^fk)*8)] = ka0;
        *(uint4*)&KPS[kh*4096 + kr*32 + ((1^fk)*8)] = ka1;
        *(uint4*)&KPS[kh*4096 + kr*32 + ((2^fk)*8)] = ka2;
        *(uint4*)&KPS[kh*4096 + kr*32 + ((3^fk)*8)] = ka3;
        *(uint4*)&VtS[vq][vr][(0^fv)*8] = va0;
        *(uint4*)&VtS[vq][vr][(1^fv)*8] = va1;
        *(uint4*)&VtS[vq][vr][(2^fv)*8] = va2;
        *(uint4*)&VtS[vq][vr][(3^fv)*8] = va3;
        __syncthreads();

        // S^T = K Q : s[j][reg] = S[qrow][key = kb + 16j + 4*h16 + reg]
        f32x4 s[8];
#pragma unroll
        for (int j=0;j<8;j++){
            const f16x8 k0 = *(const f16x8*)&KPS[       (j*16+l16)*32 + off];
            const f16x8 k1 = *(const f16x8*)&KPS[4096 + (j*16+l16)*32 + off];
            f32x4 a = (f32x4){0.f,0.f,0.f,0.f};
            a = __builtin_amdgcn_mfma_f32_16x16x32_f16(k0, q0, a, 0,0,0);
            a = __builtin_amdgcn_mfma_f32_16x16x32_f16(k1, q1, a, 0,0,0);
            s[j] = a;
        }
        if (domask && ci == nchunks-1){
#pragma unroll
            for (int j=0;j<8;j++)
#pragma unroll
                for (int reg=0;reg<4;reg++)
                    if (kb + j*16 + 4*h16 + reg > qrow)
                        s[j][reg] = -INFINITY;
        }

        // row max: 31 in-lane fmax (tree) + 2 cross-lane
        float mx01 = fmaxf(fmaxf(s[0][0],s[0][1]), fmaxf(s[0][2],s[0][3]));
        float mx1  = fmaxf(fmaxf(s[1][0],s[1][1]), fmaxf(s[1][2],s[1][3]));
        float mx2  = fmaxf(fmaxf(s[2][0],s[2][1]), fmaxf(s[2][2],s[2][3]));
        float mx3  = fmaxf(fmaxf(s[3][0],s[3][1]), fmaxf(s[3][2],s[3][3]));
        float mx4  = fmaxf(fmaxf(s[4][0],s[4][1]), fmaxf(s[4][2],s[4][3]));
        float mx5  = fmaxf(fmaxf(s[5][0],s[5][1]), fmaxf(s[5][2],s[5][3]));
        float mx6  = fmaxf(fmaxf(s[6][0],s[6][1]), fmaxf(s[6][2],s[6][3]));
        float mx7  = fmaxf(fmaxf(s[7][0],s[7][1]), fmaxf(s[7][2],s[7][3]));
        float mloc = fmaxf(fmaxf(fmaxf(mx01,mx1), fmaxf(mx2,mx3)),
                           fmaxf(fmaxf(mx4,mx5), fmaxf(mx6,mx7)));
        mloc = fmaxf(mloc, __shfl_xor(mloc,16));
        mloc = fmaxf(mloc, __shfl_xor(mloc,32));

        // defer-max: skip rescale when growth <= 8 (log2 units -> P <= 256)
        const bool small = (mloc <= m_run + 8.f);
        if (!__all(small)){
            const float mnew = fmaxf(m_run, mloc);
            const float scl  = exp2f(m_run - mnew);   // 0 on first chunk
            m_run = mnew;
            lpart *= scl;
            // accO rows are qrow-local 4*h16+reg -> gather their scales
            const float sr0 = __shfl(scl, 4*h16+0);
            const float sr1 = __shfl(scl, 4*h16+1);
            const float sr2 = __shfl(scl, 4*h16+2);
            const float sr3 = __shfl(scl, 4*h16+3);
#pragma unroll
            for (int j=0;j<4;j++){
                accO[j][0] *= sr0; accO[j][1] *= sr1;
                accO[j][2] *= sr2; accO[j][3] *= sr3;
            }
        }

        __syncthreads();   // all K reads done before P overwrites KPS

        // P = exp2(S - m); pack consecutive-key pairs; b32 swizzled stores
        const int prow = w*16 + l16;
        float ps = 0.f;
#pragma unroll
        for (int j=0;j<8;j++){
            const float p0 = exp2f(s[j][0]-m_run);
            const float p1 = exp2f(s[j][1]-m_run);
            const float p2 = exp2f(s[j][2]-m_run);
            const float p3 = exp2f(s[j][3]-m_run);
            ps += (p0+p1)+(p2+p3);
            const unsigned int u01 = pkh2(p0,p1);
            const unsigned int u23 = pkh2(p2,p3);
            const int sb = 2*(j&1) + (h16>>1);
            const int so = ((sb ^ psw)<<3) + 4*(h16&1);
            *(unsigned int*)&KPS[(j>>1)*2048 + prow*32 + so]     = u01;
            *(unsigned int*)&KPS[(j>>1)*2048 + prow*32 + so + 2] = u23;
        }
        lpart += ps;

        // O += P V (P rows wave-private; same-wave RAW via lgkmcnt)
#pragma unroll
        for (int kc=0;kc<4;kc++){
            const f16x8 pa = *(const f16x8*)&KPS[kc*2048 + (w*16+l16)*32 + off];
#pragma unroll
            for (int j=0;j<4;j++){
                const f16x8 vb_ = *(const f16x8*)&VtS[kc][j*16+l16][off];
                accO[j] = __builtin_amdgcn_mfma_f32_16x16x32_f16(pa, vb_, accO[j], 0,0,0);
            }
        }
    }

    // final denominator: reduce across the 4 lanes sharing this q-row,
    // then redistribute to accO's row keying (4*h16+reg)
    float l = lpart;
    l += __shfl_xor(l,16); l += __shfl_xor(l,32);
    const float inv = 1.0f / l;
    const float ir0 = __shfl(inv, 4*h16+0);
    const float ir1 = __shfl(inv, 4*h16+1);
    const float ir2 = __shfl(inv, 4*h16+2);
    const float ir3 = __shfl(inv, 4*h16+3);
    const int t0 = qb*64 + w*16 + 4*h16;
#pragma unroll
    for (int j=0;j<4;j++){
        const size_t base = ((size_t)b*T_ + t0)*D_ + h*HD_ + j*16 + l16;
        attb[base        ] = f2h(accO[j][0]*ir0);
        attb[base +   D_ ] = f2h(accO[j][1]*ir1);
        attb[base + 2*D_ ] = f2h(accO[j][2]*ir2);
        attb[base + 3*D_ ] = f2h(accO[j][3]*ir3);
    }
}

extern "C" void kernel_launch(void* const* d_in, const int* in_sizes, int n_in,
                              void* d_out, int out_size, void* d_ws, size_t ws_size,
                              hipStream_t stream)
{
    const float* x  = (const float*)d_in[0];
    const float* Wq = (const float*)d_in[1];
    const float* bq = (const float*)d_in[2];
    const float* Wk = (const float*)d_in[3];
    const float* bk = (const float*)d_in[4];
    const float* Wv = (const float*)d_in[5];
    const float* bv = (const float*)d_in[6];
    const float* Wo = (const float*)d_in[7];
    const float* bo = (const float*)d_in[8];
    const int* mask = (const int*)d_in[9];
    float* out = (float*)d_out;

    // workspace (72 MiB): all fp16
    unsigned short* qp  = (unsigned short*)d_ws;                 // 16 MiB
    unsigned short* kp  = qp  + (size_t)8*1024*1024;             // 16 MiB
    unsigned short* vtp = kp  + (size_t)8*1024*1024;             // 16 MiB [bh][d][t]
    unsigned short* xb  = vtp + (size_t)8*1024*1024;             // 16 MiB
    unsigned short* wt  = xb  + (size_t)8*1024*1024;             // 6 MiB
    unsigned short* wot = wt  + (size_t)3*1024*1024;             // 2 MiB
    unsigned short* attb = xb;   // alias: xb dead after gemm_qkvh

    prep_xh   <<<2048, 256, 0, stream>>>(x, xb);
    prep_wqkvh<<<dim3(16,48), 256, 0, stream>>>(Wq, Wk, Wv, wt);
    prep_woh  <<<dim3(16,16), 256, 0, stream>>>(Wo, wot);
    gemm_qkvh <<<dim3(64,24), 256, 0, stream>>>(xb, wt, bq, bk, bv, qp, kp, vtp);
    attn_mfma <<<2048, 256, 0, stream>>>(qp, kp, vtp, attb, mask);
    gemm_o    <<<dim3(64,8), 256, 0, stream>>>(attb, wot, bo, out);
}

// Round 22
// 180.450 us; speedup vs baseline: 1.0558x; 1.0558x over previous
//
#include <hip/hip_runtime.h>
#include <hip/hip_bf16.h>
#include <math.h>

#define B_  4
#define T_  2048
#define D_  1024
#define H_  16
#define HD_ 64
#define M_  8192   // B_*T_

typedef __attribute__((ext_vector_type(8))) _Float16 f16x8;
typedef __attribute__((ext_vector_type(2))) __fp16  h16x2;
typedef __attribute__((ext_vector_type(4))) float   f32x4;

static __device__ __forceinline__ unsigned short f2h(float f){
    union { _Float16 h; unsigned short u; } cv; cv.h = (_Float16)f; return cv.u;
}
static __device__ __forceinline__ unsigned int pkh2(float a, float b){
    union { h16x2 h; unsigned int u; } cv;
    cv.h = __builtin_amdgcn_cvt_pkrtz(a, b);
    return cv.u;
}
static __device__ __forceinline__ void gload_lds16(const void* g, void* l){
    __builtin_amdgcn_global_load_lds(
        (const __attribute__((address_space(1))) unsigned int*)g,
        (__attribute__((address_space(3))) unsigned int*)l, 16, 0, 0);
}

union U16x16 { unsigned short us[16]; uint4 q[2]; };
union U16x4  { unsigned short us[4];  uint2 q;    };

// ---------------------------------------------------------------------------
// prep_xh: x fp32 [8192][1024] -> xb fp16. 16 el/thread.
// ---------------------------------------------------------------------------
__global__ __launch_bounds__(256) void prep_xh(
    const float* __restrict__ x, unsigned short* __restrict__ xb)
{
    const size_t i = ((size_t)blockIdx.x*256 + threadIdx.x)*16;
    U16x16 u;
#pragma unroll
    for (int j=0;j<16;j+=4){
        float4 f = *(const float4*)(x+i+j);
        u.us[j+0]=f2h(f.x); u.us[j+1]=f2h(f.y);
        u.us[j+2]=f2h(f.z); u.us[j+3]=f2h(f.w);
    }
    *(uint4*)(xb+i)   = u.q[0];
    *(uint4*)(xb+i+8) = u.q[1];
}

// ---------------------------------------------------------------------------
// prep_wqkvh: W{q,k,v}[16][1024][64] -> wt[3072][1024] fp16 (operand-major).
// ---------------------------------------------------------------------------
__global__ __launch_bounds__(256) void prep_wqkvh(
    const float* __restrict__ Wq, const float* __restrict__ Wk,
    const float* __restrict__ Wv, unsigned short* __restrict__ wt)
{
    const int dt = blockIdx.x;
    const int zh = blockIdx.y;
    const int z = zh >> 4, h = zh & 15;
    const float* src = ((z==0)?Wq:(z==1)?Wk:Wv) + (size_t)h*1024*64;
    __shared__ float Tt[64][68];
    const int t = threadIdx.x;
    const int r = t >> 2, c4 = (t & 3) * 16;
    const float* sp = src + (size_t)(dt*64 + r)*64 + c4;
    float4 v0=*(const float4*)(sp+0), v1=*(const float4*)(sp+4);
    float4 v2=*(const float4*)(sp+8), v3=*(const float4*)(sp+12);
    *(float4*)&Tt[r][c4+ 0]=v0; *(float4*)&Tt[r][c4+ 4]=v1;
    *(float4*)&Tt[r][c4+ 8]=v2; *(float4*)&Tt[r][c4+12]=v3;
    __syncthreads();
    const int er = t >> 2, dk = (t & 3) * 16;
    U16x16 u;
#pragma unroll
    for (int j=0;j<16;j++) u.us[j] = f2h(Tt[dk+j][er]);
    unsigned short* dst = wt + (size_t)(z*1024 + h*64 + er)*1024 + dt*64 + dk;
    *(uint4*)(dst)   = u.q[0];
    *(uint4*)(dst+8) = u.q[1];
}

// ---------------------------------------------------------------------------
// prep_woh: Wo[1024][1024] -> wot[n][k] fp16.
// ---------------------------------------------------------------------------
__global__ __launch_bounds__(256) void prep_woh(
    const float* __restrict__ Wo, unsigned short* __restrict__ wot)
{
    const int kt = blockIdx.x, nt = blockIdx.y;
    __shared__ float Tt[64][68];
    const int t = threadIdx.x;
    const int r = t >> 2, c4 = (t & 3) * 16;
    const float* sp = Wo + (size_t)(kt*64 + r)*1024 + nt*64 + c4;
    float4 v0=*(const float4*)(sp+0), v1=*(const float4*)(sp+4);
    float4 v2=*(const float4*)(sp+8), v3=*(const float4*)(sp+12);
    *(float4*)&Tt[r][c4+ 0]=v0; *(float4*)&Tt[r][c4+ 4]=v1;
    *(float4*)&Tt[r][c4+ 8]=v2; *(float4*)&Tt[r][c4+12]=v3;
    __syncthreads();
    const int er = t >> 2, dk = (t & 3) * 16;
    U16x16 u;
#pragma unroll
    for (int j=0;j<16;j++) u.us[j] = f2h(Tt[dk+j][er]);
    unsigned short* dst = wot + (size_t)(nt*64 + er)*1024 + kt*64 + dk;
    *(uint4*)(dst)   = u.q[0];
    *(uint4*)(dst+8) = u.q[1];
}

// ---------------------------------------------------------------------------
// gemm_qkvh: unchanged (q scale folds 8*log2(e)).
// ---------------------------------------------------------------------------
__global__ __launch_bounds__(256) void gemm_qkvh(
    const unsigned short* __restrict__ xb, const unsigned short* __restrict__ wt,
    const float* __restrict__ bqv, const float* __restrict__ bkv,
    const float* __restrict__ bvv,
    unsigned short* __restrict__ qp, unsigned short* __restrict__ kp,
    unsigned short* __restrict__ vtp)
{
    const int m0 = blockIdx.x * 128;
    const int n0 = blockIdx.y * 128;
    const int tid = threadIdx.x;
    const int lane = tid & 63, w = tid >> 6;
    const int wr = w >> 1, wc = w & 1;
    const int fla = lane & 15, flb = lane >> 4;

    __shared__ unsigned short As[128*32];
    __shared__ unsigned short Bs[128*32];

    f32x4 acc[4][4];
#pragma unroll
    for (int i=0;i<4;i++)
#pragma unroll
        for (int j=0;j<4;j++) acc[i][j] = (f32x4){0.f,0.f,0.f,0.f};

    const int srow0 = w*32 + (lane>>2);
    const int srow1 = srow0 + 16;
    const int spc   = lane & 3;
    const size_t ga0 = (size_t)(m0+srow0)*1024 + (size_t)((spc ^ ((srow0>>1)&3))*8);
    const size_t ga1 = (size_t)(m0+srow1)*1024 + (size_t)((spc ^ ((srow1>>1)&3))*8);
    const size_t gb0 = (size_t)(n0+srow0)*1024 + (size_t)((spc ^ ((srow0>>1)&3))*8);
    const size_t gb1 = (size_t)(n0+srow1)*1024 + (size_t)((spc ^ ((srow1>>1)&3))*8);
    const int ldso0 = w*1024;          // shorts
    const int ldso1 = w*1024 + 512;
    const int pchunk = (flb ^ ((fla>>1)&3)) * 8;

    for (int ks = 0; ks < 32; ++ks){
        const size_t k0 = (size_t)ks*32;
        __syncthreads();   // prev chunk's fragment reads complete
        gload_lds16(xb + ga0 + k0, As + ldso0);
        gload_lds16(xb + ga1 + k0, As + ldso1);
        gload_lds16(wt + gb0 + k0, Bs + ldso0);
        gload_lds16(wt + gb1 + k0, Bs + ldso1);
        __syncthreads();   // vmcnt(0) drained at barrier

        f16x8 af[4], bfr[4];
#pragma unroll
        for (int mf=0; mf<4; ++mf)
            af[mf] = *(const f16x8*)&As[(wr*64+mf*16+fla)*32 + pchunk];
#pragma unroll
        for (int nf=0; nf<4; ++nf)
            bfr[nf] = *(const f16x8*)&Bs[(wc*64+nf*16+fla)*32 + pchunk];
#pragma unroll
        for (int mf=0; mf<4; ++mf)
#pragma unroll
            for (int nf=0; nf<4; ++nf)
                acc[mf][nf] = __builtin_amdgcn_mfma_f32_16x16x32_f16(
                                  af[mf], bfr[nf], acc[mf][nf], 0, 0, 0);
    }

#pragma unroll
    for (int nf=0; nf<4; ++nf){
        const int c = n0 + wc*64 + nf*16 + fla;
        const int z = c >> 10, rem = c & 1023;
        const int h = rem >> 6, e = rem & 63;
        if (z < 2){
            const float bias = ((z==0)?bqv:bkv)[rem];
            const float scl  = (z==0) ? 11.541560327111708f   // 8*log2(e)
                                      : 1.0f;
            unsigned short* op = (z==0)?qp:kp;
#pragma unroll
            for (int mf=0; mf<4; ++mf){
#pragma unroll
                for (int ri=0; ri<4; ++ri){
                    const int m = m0 + wr*64 + mf*16 + flb*4 + ri;
                    const int b = m >> 11, t = m & (T_-1);
                    op[((size_t)(b*H_ + h)*T_ + t)*HD_ + e] =
                        f2h((acc[mf][nf][ri] + bias) * scl);
                }
            }
        } else {
            const float bias = bvv[rem];
#pragma unroll
            for (int mf=0; mf<4; ++mf){
                const int m = m0 + wr*64 + mf*16 + flb*4;   // 4 consecutive t
                const int b = m >> 11, t = m & (T_-1);
                U16x4 u;
#pragma unroll
                for (int ri=0; ri<4; ++ri)
                    u.us[ri] = f2h(acc[mf][nf][ri] + bias);
                *(uint2*)(vtp + ((size_t)(b*H_ + h)*HD_ + e)*T_ + t) = u.q;
            }
        }
    }
}

// ---------------------------------------------------------------------------
// gemm_o: out = att(fp16) @ wot(fp16) + bo. (unchanged)
// ---------------------------------------------------------------------------
__global__ __launch_bounds__(256) void gemm_o(
    const unsigned short* __restrict__ attb, const unsigned short* __restrict__ wot,
    const float* __restrict__ bo, float* __restrict__ out)
{
    const int m0 = blockIdx.x * 128;
    const int n0 = blockIdx.y * 128;
    const int tid = threadIdx.x;
    const int lane = tid & 63, w = tid >> 6;
    const int wr = w >> 1, wc = w & 1;
    const int fla = lane & 15, flb = lane >> 4;

    __shared__ unsigned short As[4096];
    __shared__ unsigned short Bs[4096];

    f32x4 acc[4][4];
#pragma unroll
    for (int i=0;i<4;i++)
#pragma unroll
        for (int j=0;j<4;j++) acc[i][j] = (f32x4){0.f,0.f,0.f,0.f};

    const int srow0 = w*32 + (lane>>2);
    const int srow1 = srow0 + 16;
    const int spc   = lane & 3;
    const size_t ga0 = (size_t)(m0+srow0)*1024 + (size_t)((spc ^ ((srow0>>1)&3))*8);
    const size_t ga1 = (size_t)(m0+srow1)*1024 + (size_t)((spc ^ ((srow1>>1)&3))*8);
    const size_t gb0 = (size_t)(n0+srow0)*1024 + (size_t)((spc ^ ((srow0>>1)&3))*8);
    const size_t gb1 = (size_t)(n0+srow1)*1024 + (size_t)((spc ^ ((srow1>>1)&3))*8);
    const int ldso0 = w*1024;
    const int ldso1 = w*1024 + 512;
    const int pchunk = (flb ^ ((fla>>1)&3)) * 8;

    for (int ks = 0; ks < 32; ++ks){
        const size_t k0 = (size_t)ks*32;
        __syncthreads();
        gload_lds16(attb + ga0 + k0, As + ldso0);
        gload_lds16(attb + ga1 + k0, As + ldso1);
        gload_lds16(wot  + gb0 + k0, Bs + ldso0);
        gload_lds16(wot  + gb1 + k0, Bs + ldso1);
        __syncthreads();

        f16x8 af[4], bfr[4];
#pragma unroll
        for (int mf=0; mf<4; ++mf)
            af[mf] = *(const f16x8*)&As[(wr*64+mf*16+fla)*32 + pchunk];
#pragma unroll
        for (int nf=0; nf<4; ++nf)
            bfr[nf] = *(const f16x8*)&Bs[(wc*64+nf*16+fla)*32 + pchunk];
#pragma unroll
        for (int mf=0; mf<4; ++mf)
#pragma unroll
            for (int nf=0; nf<4; ++nf)
                acc[mf][nf] = __builtin_amdgcn_mfma_f32_16x16x32_f16(
                                  af[mf], bfr[nf], acc[mf][nf], 0, 0, 0);
    }

#pragma unroll
    for (int nf=0; nf<4; ++nf){
        const int n = n0 + wc*64 + nf*16 + fla;
        const float bias = bo[n];
#pragma unroll
        for (int mf=0; mf<4; ++mf){
#pragma unroll
            for (int ri=0; ri<4; ++ri){
                const int m = m0 + wr*64 + mf*16 + flb*4 + ri;
                out[(size_t)m*D_ + n] = acc[mf][nf][ri] + bias;
            }
        }
    }
}

// ---------------------------------------------------------------------------
// MFMA flash attention, fp16, exp2-domain, KVBLK=128, swapped QK^T,
// 128 Q-ROWS / BLOCK (8 waves, 512 thr): each chunk's staging + barriers
// serve 2x the q-rows (1024 blocks total; K/V re-fetch traffic halves).
// K (16KB) overlaid by P (32KB) in KPS; V 16KB -> LDS 48KB, 3 blocks/CU.
// Per-wave inner logic identical to R20/21 (lane-local softmax row).
// ---------------------------------------------------------------------------
__global__ __launch_bounds__(512) void attn_mfma(
    const unsigned short* __restrict__ qp, const unsigned short* __restrict__ kp,
    const unsigned short* __restrict__ vtp, unsigned short* __restrict__ attb,
    const int* __restrict__ maskp)
{
    const int bid = blockIdx.x;
    const int qb2 = 15 - (bid >> 6);   // big q-blocks first (128 rows each)
    const int bh  = bid & 63;
    const int b   = bh >> 4, h = bh & 15;
    const int tid = threadIdx.x;
    const int lane = tid & 63, w = tid >> 6;      // w = 0..7
    const int l16 = lane & 15, h16 = lane >> 4;
    const int domask = maskp[0];

    __shared__ unsigned short KPS[16384];        // K (16KB), then P (32KB)
    __shared__ unsigned short VtS[4][64][32];    // [key-chunk][d][key%32]

    const int qrow = qb2*128 + w*16 + l16;       // this lane's softmax row
    const size_t qoff = ((size_t)bh*T_ + qrow)*HD_ + 8*h16;
    const f16x8 q0 = *(const f16x8*)(qp + qoff);
    const f16x8 q1 = *(const f16x8*)(qp + qoff + 32);

    f32x4 accO[4];
#pragma unroll
    for (int j=0;j<4;j++) accO[j] = (f32x4){0.f,0.f,0.f,0.f};
    float m_run = -INFINITY, lpart = 0.f;

    // staging geometry (512 threads, 2 uint4 each per operand)
    const int kr  = tid >> 2;          // 0..127 key row (K)
    const int kq  = tid & 3;           // d-16-segment
    const int kh  = kq >> 1;           // d-half
    const int ksb = (kq & 1) * 2;      // first logical sub-block
    const int fk  = (kr >> 1) & 3;
    const int vr  = tid >> 3;          // 0..63 d row (V)
    const int vs8 = tid & 7;           // key-16-segment
    const int vq  = vs8 >> 1;          // key quarter
    const int vsb = (vs8 & 1) * 2;
    const int fv  = (vr >> 1) & 3;

    // fragment-read swizzle (all fragment rows == l16 mod 16; +16k terms == 0 mod 4)
    const int off = (h16 ^ ((l16>>1)&3)) * 8;
    const int psw = (l16>>1)&3;        // P-row swizzle key (row = w*16+l16)

    const size_t kbase = (size_t)bh*T_*HD_;
    const size_t vbase = (size_t)bh*HD_*T_;

    const int nchunks = domask ? (qb2+1) : 16;
    for (int ci = 0; ci < nchunks; ++ci){
        const int kb = ci << 7;
        const unsigned short* ksrc = kp + kbase + (size_t)(kb+kr)*HD_ + kq*16;
        uint4 ka0=*(const uint4*)(ksrc), ka1=*(const uint4*)(ksrc+8);
        const unsigned short* vsrc = vtp + vbase + (size_t)vr*T_ + kb + vs8*16;
        uint4 va0=*(const uint4*)(vsrc), va1=*(const uint4*)(vsrc+8);
        __syncthreads();   // prev chunk's PV reads (KPS=P rows, VtS) complete
        *(uint4*)&KPS[kh*4096 + kr*32 + (((ksb  )^fk)*8)] = ka0;
        *(uint4*)&KPS[kh*4096 + kr*32 + (((ksb+1)^fk)*8)] = ka1;
        *(uint4*)&VtS[vq][vr][((vsb  )^fv)*8] = va0;
        *(uint4*)&VtS[vq][vr][((vsb+1)^fv)*8] = va1;
        __syncthreads();

        // S^T = K Q : s[j][reg] = S[qrow][key = kb + 16j + 4*h16 + reg]
        f32x4 s[8];
#pragma unroll
        for (int j=0;j<8;j++){
            const f16x8 k0 = *(const f16x8*)&KPS[       (j*16+l16)*32 + off];
            const f16x8 k1 = *(const f16x8*)&KPS[4096 + (j*16+l16)*32 + off];
            f32x4 a = (f32x4){0.f,0.f,0.f,0.f};
            a = __builtin_amdgcn_mfma_f32_16x16x32_f16(k0, q0, a, 0,0,0);
            a = __builtin_amdgcn_mfma_f32_16x16x32_f16(k1, q1, a, 0,0,0);
            s[j] = a;
        }
        if (domask && ci == nchunks-1){
#pragma unroll
            for (int j=0;j<8;j++)
#pragma unroll
                for (int reg=0;reg<4;reg++)
                    if (kb + j*16 + 4*h16 + reg > qrow)
                        s[j][reg] = -INFINITY;
        }

        // row max: 31 in-lane fmax (tree) + 2 cross-lane
        float mx01 = fmaxf(fmaxf(s[0][0],s[0][1]), fmaxf(s[0][2],s[0][3]));
        float mx1  = fmaxf(fmaxf(s[1][0],s[1][1]), fmaxf(s[1][2],s[1][3]));
        float mx2  = fmaxf(fmaxf(s[2][0],s[2][1]), fmaxf(s[2][2],s[2][3]));
        float mx3  = fmaxf(fmaxf(s[3][0],s[3][1]), fmaxf(s[3][2],s[3][3]));
        float mx4  = fmaxf(fmaxf(s[4][0],s[4][1]), fmaxf(s[4][2],s[4][3]));
        float mx5  = fmaxf(fmaxf(s[5][0],s[5][1]), fmaxf(s[5][2],s[5][3]));
        float mx6  = fmaxf(fmaxf(s[6][0],s[6][1]), fmaxf(s[6][2],s[6][3]));
        float mx7  = fmaxf(fmaxf(s[7][0],s[7][1]), fmaxf(s[7][2],s[7][3]));
        float mloc = fmaxf(fmaxf(fmaxf(mx01,mx1), fmaxf(mx2,mx3)),
                           fmaxf(fmaxf(mx4,mx5), fmaxf(mx6,mx7)));
        mloc = fmaxf(mloc, __shfl_xor(mloc,16));
        mloc = fmaxf(mloc, __shfl_xor(mloc,32));

        // defer-max: skip rescale when growth <= 8 (log2 units -> P <= 256)
        const bool small = (mloc <= m_run + 8.f);
        if (!__all(small)){
            const float mnew = fmaxf(m_run, mloc);
            const float scl  = exp2f(m_run - mnew);   // 0 on first chunk
            m_run = mnew;
            lpart *= scl;
            const float sr0 = __shfl(scl, 4*h16+0);
            const float sr1 = __shfl(scl, 4*h16+1);
            const float sr2 = __shfl(scl, 4*h16+2);
            const float sr3 = __shfl(scl, 4*h16+3);
#pragma unroll
            for (int j=0;j<4;j++){
                accO[j][0] *= sr0; accO[j][1] *= sr1;
                accO[j][2] *= sr2; accO[j][3] *= sr3;
            }
        }

        __syncthreads();   // all K reads done before P overwrites KPS

        // P = exp2(S - m); pack consecutive-key pairs; b32 swizzled stores
        const int prow = w*16 + l16;               // 0..127
        float ps = 0.f;
#pragma unroll
        for (int j=0;j<8;j++){
            const float p0 = exp2f(s[j][0]-m_run);
            const float p1 = exp2f(s[j][1]-m_run);
            const float p2 = exp2f(s[j][2]-m_run);
            const float p3 = exp2f(s[j][3]-m_run);
            ps += (p0+p1)+(p2+p3);
            const unsigned int u01 = pkh2(p0,p1);
            const unsigned int u23 = pkh2(p2,p3);
            const int sb = 2*(j&1) + (h16>>1);
            const int so = ((sb ^ psw)<<3) + 4*(h16&1);
            *(unsigned int*)&KPS[(j>>1)*4096 + prow*32 + so]     = u01;
            *(unsigned int*)&KPS[(j>>1)*4096 + prow*32 + so + 2] = u23;
        }
        lpart += ps;

        // O += P V (P rows wave-private; same-wave RAW via lgkmcnt)
#pragma unroll
        for (int kc=0;kc<4;kc++){
            const f16x8 pa = *(const f16x8*)&KPS[kc*4096 + (w*16+l16)*32 + off];
#pragma unroll
            for (int j=0;j<4;j++){
                const f16x8 vb_ = *(const f16x8*)&VtS[kc][j*16+l16][off];
                accO[j] = __builtin_amdgcn_mfma_f32_16x16x32_f16(pa, vb_, accO[j], 0,0,0);
            }
        }
    }

    // final denominator: reduce across the 4 lanes sharing this q-row,
    // then redistribute to accO's row keying (4*h16+reg)
    float l = lpart;
    l += __shfl_xor(l,16); l += __shfl_xor(l,32);
    const float inv = 1.0f / l;
    const float ir0 = __shfl(inv, 4*h16+0);
    const float ir1 = __shfl(inv, 4*h16+1);
    const float ir2 = __shfl(inv, 4*h16+2);
    const float ir3 = __shfl(inv, 4*h16+3);
    const int t0 = qb2*128 + w*16 + 4*h16;
#pragma unroll
    for (int j=0;j<4;j++){
        const size_t base = ((size_t)b*T_ + t0)*D_ + h*HD_ + j*16 + l16;
        attb[base        ] = f2h(accO[j][0]*ir0);
        attb[base +   D_ ] = f2h(accO[j][1]*ir1);
        attb[base + 2*D_ ] = f2h(accO[j][2]*ir2);
        attb[base + 3*D_ ] = f2h(accO[j][3]*ir3);
    }
}

extern "C" void kernel_launch(void* const* d_in, const int* in_sizes, int n_in,
                              void* d_out, int out_size, void* d_ws, size_t ws_size,
                              hipStream_t stream)
{
    const float* x  = (const float*)d_in[0];
    const float* Wq = (const float*)d_in[1];
    const float* bq = (const float*)d_in[2];
    const float* Wk = (const float*)d_in[3];
    const float* bk = (const float*)d_in[4];
    const float* Wv = (const float*)d_in[5];
    const float* bv = (const float*)d_in[6];
    const float* Wo = (const float*)d_in[7];
    const float* bo = (const float*)d_in[8];
    const int* mask = (const int*)d_in[9];
    float* out = (float*)d_out;

    // workspace (72 MiB): all fp16
    unsigned short* qp  = (unsigned short*)d_ws;                 // 16 MiB
    unsigned short* kp  = qp  + (size_t)8*1024*1024;             // 16 MiB
    unsigned short* vtp = kp  + (size_t)8*1024*1024;             // 16 MiB [bh][d][t]
    unsigned short* xb  = vtp + (size_t)8*1024*1024;             // 16 MiB
    unsigned short* wt  = xb  + (size_t)8*1024*1024;             // 6 MiB
    unsigned short* wot = wt  + (size_t)3*1024*1024;             // 2 MiB
    unsigned short* attb = xb;   // alias: xb dead after gemm_qkvh

    prep_xh   <<<2048, 256, 0, stream>>>(x, xb);
    prep_wqkvh<<<dim3(16,48), 256, 0, stream>>>(Wq, Wk, Wv, wt);
    prep_woh  <<<dim3(16,16), 256, 0, stream>>>(Wo, wot);
    gemm_qkvh <<<dim3(64,24), 256, 0, stream>>>(xb, wt, bq, bk, bv, qp, kp, vtp);
    attn_mfma <<<1024, 512, 0, stream>>>(qp, kp, vtp, attb, mask);
    gemm_o    <<<dim3(64,8), 256, 0, stream>>>(attb, wot, bo, out);
}

// Round 23
// 179.752 us; speedup vs baseline: 1.0599x; 1.0039x over previous
//
#include <hip/hip_runtime.h>
#include <hip/hip_bf16.h>
#include <math.h>

#define B_  4
#define T_  2048
#define D_  1024
#define H_  16
#define HD_ 64
#define M_  8192   // B_*T_

typedef __attribute__((ext_vector_type(8))) _Float16 f16x8;
typedef __attribute__((ext_vector_type(2))) __fp16  h16x2;
typedef __attribute__((ext_vector_type(4))) float   f32x4;

static __device__ __forceinline__ unsigned short f2h(float f){
    union { _Float16 h; unsigned short u; } cv; cv.h = (_Float16)f; return cv.u;
}
static __device__ __forceinline__ unsigned int pkh2(float a, float b){
    union { h16x2 h; unsigned int u; } cv;
    cv.h = __builtin_amdgcn_cvt_pkrtz(a, b);
    return cv.u;
}
static __device__ __forceinline__ void gload_lds16(const void* g, void* l){
    __builtin_amdgcn_global_load_lds(
        (const __attribute__((address_space(1))) unsigned int*)g,
        (__attribute__((address_space(3))) unsigned int*)l, 16, 0, 0);
}

union U16x16 { unsigned short us[16]; uint4 q[2]; };
union U16x4  { unsigned short us[4];  uint2 q;    };

// ---------------------------------------------------------------------------
// prep_all: one kernel, 3072 blocks.
//   [0,2048):    x fp32 -> xb fp16 (16 el/thread)
//   [2048,2816): W{q,k,v} -> wt[3072][1024] fp16 operand-major (LDS transpose)
//   [2816,3072): Wo -> wot[n][k] fp16 (LDS transpose)
// ---------------------------------------------------------------------------
__global__ __launch_bounds__(256) void prep_all(
    const float* __restrict__ x,
    const float* __restrict__ Wq, const float* __restrict__ Wk,
    const float* __restrict__ Wv, const float* __restrict__ Wo,
    unsigned short* __restrict__ xb, unsigned short* __restrict__ wt,
    unsigned short* __restrict__ wot)
{
    const int bid = blockIdx.x;
    const int t = threadIdx.x;

    if (bid < 2048){
        const size_t i = ((size_t)bid*256 + t)*16;
        U16x16 u;
#pragma unroll
        for (int j=0;j<16;j+=4){
            float4 f = *(const float4*)(x+i+j);
            u.us[j+0]=f2h(f.x); u.us[j+1]=f2h(f.y);
            u.us[j+2]=f2h(f.z); u.us[j+3]=f2h(f.w);
        }
        *(uint4*)(xb+i)   = u.q[0];
        *(uint4*)(xb+i+8) = u.q[1];
        return;
    }

    __shared__ float Tt[64][68];
    const int r = t >> 2, c4 = (t & 3) * 16;
    const int er = t >> 2, dk = (t & 3) * 16;

    if (bid < 2816){
        const int lb = bid - 2048;
        const int dt = lb & 15;
        const int zh = lb >> 4;
        const int z = zh >> 4, h = zh & 15;
        const float* src = ((z==0)?Wq:(z==1)?Wk:Wv) + (size_t)h*1024*64;
        const float* sp = src + (size_t)(dt*64 + r)*64 + c4;
        float4 v0=*(const float4*)(sp+0), v1=*(const float4*)(sp+4);
        float4 v2=*(const float4*)(sp+8), v3=*(const float4*)(sp+12);
        *(float4*)&Tt[r][c4+ 0]=v0; *(float4*)&Tt[r][c4+ 4]=v1;
        *(float4*)&Tt[r][c4+ 8]=v2; *(float4*)&Tt[r][c4+12]=v3;
        __syncthreads();
        U16x16 u;
#pragma unroll
        for (int j=0;j<16;j++) u.us[j] = f2h(Tt[dk+j][er]);
        unsigned short* dst = wt + (size_t)(z*1024 + h*64 + er)*1024 + dt*64 + dk;
        *(uint4*)(dst)   = u.q[0];
        *(uint4*)(dst+8) = u.q[1];
    } else {
        const int lb = bid - 2816;
        const int kt = lb & 15, nt = lb >> 4;
        const float* sp = Wo + (size_t)(kt*64 + r)*1024 + nt*64 + c4;
        float4 v0=*(const float4*)(sp+0), v1=*(const float4*)(sp+4);
        float4 v2=*(const float4*)(sp+8), v3=*(const float4*)(sp+12);
        *(float4*)&Tt[r][c4+ 0]=v0; *(float4*)&Tt[r][c4+ 4]=v1;
        *(float4*)&Tt[r][c4+ 8]=v2; *(float4*)&Tt[r][c4+12]=v3;
        __syncthreads();
        U16x16 u;
#pragma unroll
        for (int j=0;j<16;j++) u.us[j] = f2h(Tt[dk+j][er]);
        unsigned short* dst = wot + (size_t)(nt*64 + er)*1024 + kt*64 + dk;
        *(uint4*)(dst)   = u.q[0];
        *(uint4*)(dst+8) = u.q[1];
    }
}

// ---------------------------------------------------------------------------
// gemm_qkvh: unchanged (q scale folds 8*log2(e)).
// ---------------------------------------------------------------------------
__global__ __launch_bounds__(256) void gemm_qkvh(
    const unsigned short* __restrict__ xb, const unsigned short* __restrict__ wt,
    const float* __restrict__ bqv, const float* __restrict__ bkv,
    const float* __restrict__ bvv,
    unsigned short* __restrict__ qp, unsigned short* __restrict__ kp,
    unsigned short* __restrict__ vtp)
{
    const int m0 = blockIdx.x * 128;
    const int n0 = blockIdx.y * 128;
    const int tid = threadIdx.x;
    const int lane = tid & 63, w = tid >> 6;
    const int wr = w >> 1, wc = w & 1;
    const int fla = lane & 15, flb = lane >> 4;

    __shared__ unsigned short As[128*32];
    __shared__ unsigned short Bs[128*32];

    f32x4 acc[4][4];
#pragma unroll
    for (int i=0;i<4;i++)
#pragma unroll
        for (int j=0;j<4;j++) acc[i][j] = (f32x4){0.f,0.f,0.f,0.f};

    const int srow0 = w*32 + (lane>>2);
    const int srow1 = srow0 + 16;
    const int spc   = lane & 3;
    const size_t ga0 = (size_t)(m0+srow0)*1024 + (size_t)((spc ^ ((srow0>>1)&3))*8);
    const size_t ga1 = (size_t)(m0+srow1)*1024 + (size_t)((spc ^ ((srow1>>1)&3))*8);
    const size_t gb0 = (size_t)(n0+srow0)*1024 + (size_t)((spc ^ ((srow0>>1)&3))*8);
    const size_t gb1 = (size_t)(n0+srow1)*1024 + (size_t)((spc ^ ((srow1>>1)&3))*8);
    const int ldso0 = w*1024;          // shorts
    const int ldso1 = w*1024 + 512;
    const int pchunk = (flb ^ ((fla>>1)&3)) * 8;

    for (int ks = 0; ks < 32; ++ks){
        const size_t k0 = (size_t)ks*32;
        __syncthreads();   // prev chunk's fragment reads complete
        gload_lds16(xb + ga0 + k0, As + ldso0);
        gload_lds16(xb + ga1 + k0, As + ldso1);
        gload_lds16(wt + gb0 + k0, Bs + ldso0);
        gload_lds16(wt + gb1 + k0, Bs + ldso1);
        __syncthreads();   // vmcnt(0) drained at barrier

        f16x8 af[4], bfr[4];
#pragma unroll
        for (int mf=0; mf<4; ++mf)
            af[mf] = *(const f16x8*)&As[(wr*64+mf*16+fla)*32 + pchunk];
#pragma unroll
        for (int nf=0; nf<4; ++nf)
            bfr[nf] = *(const f16x8*)&Bs[(wc*64+nf*16+fla)*32 + pchunk];
#pragma unroll
        for (int mf=0; mf<4; ++mf)
#pragma unroll
            for (int nf=0; nf<4; ++nf)
                acc[mf][nf] = __builtin_amdgcn_mfma_f32_16x16x32_f16(
                                  af[mf], bfr[nf], acc[mf][nf], 0, 0, 0);
    }

#pragma unroll
    for (int nf=0; nf<4; ++nf){
        const int c = n0 + wc*64 + nf*16 + fla;
        const int z = c >> 10, rem = c & 1023;
        const int h = rem >> 6, e = rem & 63;
        if (z < 2){
            const float bias = ((z==0)?bqv:bkv)[rem];
            const float scl  = (z==0) ? 11.541560327111708f   // 8*log2(e)
                                      : 1.0f;
            unsigned short* op = (z==0)?qp:kp;
#pragma unroll
            for (int mf=0; mf<4; ++mf){
#pragma unroll
                for (int ri=0; ri<4; ++ri){
                    const int m = m0 + wr*64 + mf*16 + flb*4 + ri;
                    const int b = m >> 11, t = m & (T_-1);
                    op[((size_t)(b*H_ + h)*T_ + t)*HD_ + e] =
                        f2h((acc[mf][nf][ri] + bias) * scl);
                }
            }
        } else {
            const float bias = bvv[rem];
#pragma unroll
            for (int mf=0; mf<4; ++mf){
                const int m = m0 + wr*64 + mf*16 + flb*4;   // 4 consecutive t
                const int b = m >> 11, t = m & (T_-1);
                U16x4 u;
#pragma unroll
                for (int ri=0; ri<4; ++ri)
                    u.us[ri] = f2h(acc[mf][nf][ri] + bias);
                *(uint2*)(vtp + ((size_t)(b*H_ + h)*HD_ + e)*T_ + t) = u.q;
            }
        }
    }
}

// ---------------------------------------------------------------------------
// gemm_o: out = att(fp16) @ wot(fp16) + bo. (unchanged)
// ---------------------------------------------------------------------------
__global__ __launch_bounds__(256) void gemm_o(
    const unsigned short* __restrict__ attb, const unsigned short* __restrict__ wot,
    const float* __restrict__ bo, float* __restrict__ out)
{
    const int m0 = blockIdx.x * 128;
    const int n0 = blockIdx.y * 128;
    const int tid = threadIdx.x;
    const int lane = tid & 63, w = tid >> 6;
    const int wr = w >> 1, wc = w & 1;
    const int fla = lane & 15, flb = lane >> 4;

    __shared__ unsigned short As[4096];
    __shared__ unsigned short Bs[4096];

    f32x4 acc[4][4];
#pragma unroll
    for (int i=0;i<4;i++)
#pragma unroll
        for (int j=0;j<4;j++) acc[i][j] = (f32x4){0.f,0.f,0.f,0.f};

    const int srow0 = w*32 + (lane>>2);
    const int srow1 = srow0 + 16;
    const int spc   = lane & 3;
    const size_t ga0 = (size_t)(m0+srow0)*1024 + (size_t)((spc ^ ((srow0>>1)&3))*8);
    const size_t ga1 = (size_t)(m0+srow1)*1024 + (size_t)((spc ^ ((srow1>>1)&3))*8);
    const size_t gb0 = (size_t)(n0+srow0)*1024 + (size_t)((spc ^ ((srow0>>1)&3))*8);
    const size_t gb1 = (size_t)(n0+srow1)*1024 + (size_t)((spc ^ ((srow1>>1)&3))*8);
    const int ldso0 = w*1024;
    const int ldso1 = w*1024 + 512;
    const int pchunk = (flb ^ ((fla>>1)&3)) * 8;

    for (int ks = 0; ks < 32; ++ks){
        const size_t k0 = (size_t)ks*32;
        __syncthreads();
        gload_lds16(attb + ga0 + k0, As + ldso0);
        gload_lds16(attb + ga1 + k0, As + ldso1);
        gload_lds16(wot  + gb0 + k0, Bs + ldso0);
        gload_lds16(wot  + gb1 + k0, Bs + ldso1);
        __syncthreads();

        f16x8 af[4], bfr[4];
#pragma unroll
        for (int mf=0; mf<4; ++mf)
            af[mf] = *(const f16x8*)&As[(wr*64+mf*16+fla)*32 + pchunk];
#pragma unroll
        for (int nf=0; nf<4; ++nf)
            bfr[nf] = *(const f16x8*)&Bs[(wc*64+nf*16+fla)*32 + pchunk];
#pragma unroll
        for (int mf=0; mf<4; ++mf)
#pragma unroll
            for (int nf=0; nf<4; ++nf)
                acc[mf][nf] = __builtin_amdgcn_mfma_f32_16x16x32_f16(
                                  af[mf], bfr[nf], acc[mf][nf], 0, 0, 0);
    }

#pragma unroll
    for (int nf=0; nf<4; ++nf){
        const int n = n0 + wc*64 + nf*16 + fla;
        const float bias = bo[n];
#pragma unroll
        for (int mf=0; mf<4; ++mf){
#pragma unroll
            for (int ri=0; ri<4; ++ri){
                const int m = m0 + wr*64 + mf*16 + flb*4 + ri;
                out[(size_t)m*D_ + n] = acc[mf][nf][ri] + bias;
            }
        }
    }
}

// ---------------------------------------------------------------------------
// MFMA flash attention, fp16, exp2-domain, KVBLK=128, swapped QK^T,
// 128 q-rows/block (8 waves, 512 thr), K overlaid by P in KPS. (unchanged)
// ---------------------------------------------------------------------------
__global__ __launch_bounds__(512) void attn_mfma(
    const unsigned short* __restrict__ qp, const unsigned short* __restrict__ kp,
    const unsigned short* __restrict__ vtp, unsigned short* __restrict__ attb,
    const int* __restrict__ maskp)
{
    const int bid = blockIdx.x;
    const int qb2 = 15 - (bid >> 6);   // big q-blocks first (128 rows each)
    const int bh  = bid & 63;
    const int b   = bh >> 4, h = bh & 15;
    const int tid = threadIdx.x;
    const int lane = tid & 63, w = tid >> 6;      // w = 0..7
    const int l16 = lane & 15, h16 = lane >> 4;
    const int domask = maskp[0];

    __shared__ unsigned short KPS[16384];        // K (16KB), then P (32KB)
    __shared__ unsigned short VtS[4][64][32];    // [key-chunk][d][key%32]

    const int qrow = qb2*128 + w*16 + l16;       // this lane's softmax row
    const size_t qoff = ((size_t)bh*T_ + qrow)*HD_ + 8*h16;
    const f16x8 q0 = *(const f16x8*)(qp + qoff);
    const f16x8 q1 = *(const f16x8*)(qp + qoff + 32);

    f32x4 accO[4];
#pragma unroll
    for (int j=0;j<4;j++) accO[j] = (f32x4){0.f,0.f,0.f,0.f};
    float m_run = -INFINITY, lpart = 0.f;

    // staging geometry (512 threads, 2 uint4 each per operand)
    const int kr  = tid >> 2;          // 0..127 key row (K)
    const int kq  = tid & 3;           // d-16-segment
    const int kh  = kq >> 1;           // d-half
    const int ksb = (kq & 1) * 2;      // first logical sub-block
    const int fk  = (kr >> 1) & 3;
    const int vr  = tid >> 3;          // 0..63 d row (V)
    const int vs8 = tid & 7;           // key-16-segment
    const int vq  = vs8 >> 1;          // key quarter
    const int vsb = (vs8 & 1) * 2;
    const int fv  = (vr >> 1) & 3;

    // fragment-read swizzle (all fragment rows == l16 mod 16)
    const int off = (h16 ^ ((l16>>1)&3)) * 8;
    const int psw = (l16>>1)&3;        // P-row swizzle key (row = w*16+l16)

    const size_t kbase = (size_t)bh*T_*HD_;
    const size_t vbase = (size_t)bh*HD_*T_;

    const int nchunks = domask ? (qb2+1) : 16;
    for (int ci = 0; ci < nchunks; ++ci){
        const int kb = ci << 7;
        const unsigned short* ksrc = kp + kbase + (size_t)(kb+kr)*HD_ + kq*16;
        uint4 ka0=*(const uint4*)(ksrc), ka1=*(const uint4*)(ksrc+8);
        const unsigned short* vsrc = vtp + vbase + (size_t)vr*T_ + kb + vs8*16;
        uint4 va0=*(const uint4*)(vsrc), va1=*(const uint4*)(vsrc+8);
        __syncthreads();   // prev chunk's PV reads (KPS=P rows, VtS) complete
        *(uint4*)&KPS[kh*4096 + kr*32 + (((ksb  )^fk)*8)] = ka0;
        *(uint4*)&KPS[kh*4096 + kr*32 + (((ksb+1)^fk)*8)] = ka1;
        *(uint4*)&VtS[vq][vr][((vsb  )^fv)*8] = va0;
        *(uint4*)&VtS[vq][vr][((vsb+1)^fv)*8] = va1;
        __syncthreads();

        // S^T = K Q : s[j][reg] = S[qrow][key = kb + 16j + 4*h16 + reg]
        f32x4 s[8];
#pragma unroll
        for (int j=0;j<8;j++){
            const f16x8 k0 = *(const f16x8*)&KPS[       (j*16+l16)*32 + off];
            const f16x8 k1 = *(const f16x8*)&KPS[4096 + (j*16+l16)*32 + off];
            f32x4 a = (f32x4){0.f,0.f,0.f,0.f};
            a = __builtin_amdgcn_mfma_f32_16x16x32_f16(k0, q0, a, 0,0,0);
            a = __builtin_amdgcn_mfma_f32_16x16x32_f16(k1, q1, a, 0,0,0);
            s[j] = a;
        }
        if (domask && ci == nchunks-1){
#pragma unroll
            for (int j=0;j<8;j++)
#pragma unroll
                for (int reg=0;reg<4;reg++)
                    if (kb + j*16 + 4*h16 + reg > qrow)
                        s[j][reg] = -INFINITY;
        }

        // row max: 31 in-lane fmax (tree) + 2 cross-lane
        float mx01 = fmaxf(fmaxf(s[0][0],s[0][1]), fmaxf(s[0][2],s[0][3]));
        float mx1  = fmaxf(fmaxf(s[1][0],s[1][1]), fmaxf(s[1][2],s[1][3]));
        float mx2  = fmaxf(fmaxf(s[2][0],s[2][1]), fmaxf(s[2][2],s[2][3]));
        float mx3  = fmaxf(fmaxf(s[3][0],s[3][1]), fmaxf(s[3][2],s[3][3]));
        float mx4  = fmaxf(fmaxf(s[4][0],s[4][1]), fmaxf(s[4][2],s[4][3]));
        float mx5  = fmaxf(fmaxf(s[5][0],s[5][1]), fmaxf(s[5][2],s[5][3]));
        float mx6  = fmaxf(fmaxf(s[6][0],s[6][1]), fmaxf(s[6][2],s[6][3]));
        float mx7  = fmaxf(fmaxf(s[7][0],s[7][1]), fmaxf(s[7][2],s[7][3]));
        float mloc = fmaxf(fmaxf(fmaxf(mx01,mx1), fmaxf(mx2,mx3)),
                           fmaxf(fmaxf(mx4,mx5), fmaxf(mx6,mx7)));
        mloc = fmaxf(mloc, __shfl_xor(mloc,16));
        mloc = fmaxf(mloc, __shfl_xor(mloc,32));

        // defer-max: skip rescale when growth <= 8 (log2 units -> P <= 256)
        const bool small = (mloc <= m_run + 8.f);
        if (!__all(small)){
            const float mnew = fmaxf(m_run, mloc);
            const float scl  = exp2f(m_run - mnew);   // 0 on first chunk
            m_run = mnew;
            lpart *= scl;
            const float sr0 = __shfl(scl, 4*h16+0);
            const float sr1 = __shfl(scl, 4*h16+1);
            const float sr2 = __shfl(scl, 4*h16+2);
            const float sr3 = __shfl(scl, 4*h16+3);
#pragma unroll
            for (int j=0;j<4;j++){
                accO[j][0] *= sr0; accO[j][1] *= sr1;
                accO[j][2] *= sr2; accO[j][3] *= sr3;
            }
        }

        __syncthreads();   // all K reads done before P overwrites KPS

        // P = exp2(S - m); pack consecutive-key pairs; b32 swizzled stores
        const int prow = w*16 + l16;               // 0..127
        float ps = 0.f;
#pragma unroll
        for (int j=0;j<8;j++){
            const float p0 = exp2f(s[j][0]-m_run);
            const float p1 = exp2f(s[j][1]-m_run);
            const float p2 = exp2f(s[j][2]-m_run);
            const float p3 = exp2f(s[j][3]-m_run);
            ps += (p0+p1)+(p2+p3);
            const unsigned int u01 = pkh2(p0,p1);
            const unsigned int u23 = pkh2(p2,p3);
            const int sb = 2*(j&1) + (h16>>1);
            const int so = ((sb ^ psw)<<3) + 4*(h16&1);
            *(unsigned int*)&KPS[(j>>1)*4096 + prow*32 + so]     = u01;
            *(unsigned int*)&KPS[(j>>1)*4096 + prow*32 + so + 2] = u23;
        }
        lpart += ps;

        // O += P V (P rows wave-private; same-wave RAW via lgkmcnt)
#pragma unroll
        for (int kc=0;kc<4;kc++){
            const f16x8 pa = *(const f16x8*)&KPS[kc*4096 + (w*16+l16)*32 + off];
#pragma unroll
            for (int j=0;j<4;j++){
                const f16x8 vb_ = *(const f16x8*)&VtS[kc][j*16+l16][off];
                accO[j] = __builtin_amdgcn_mfma_f32_16x16x32_f16(pa, vb_, accO[j], 0,0,0);
            }
        }
    }

    // final denominator: reduce across the 4 lanes sharing this q-row,
    // then redistribute to accO's row keying (4*h16+reg)
    float l = lpart;
    l += __shfl_xor(l,16); l += __shfl_xor(l,32);
    const float inv = 1.0f / l;
    const float ir0 = __shfl(inv, 4*h16+0);
    const float ir1 = __shfl(inv, 4*h16+1);
    const float ir2 = __shfl(inv, 4*h16+2);
    const float ir3 = __shfl(inv, 4*h16+3);
    const int t0 = qb2*128 + w*16 + 4*h16;
#pragma unroll
    for (int j=0;j<4;j++){
        const size_t base = ((size_t)b*T_ + t0)*D_ + h*HD_ + j*16 + l16;
        attb[base        ] = f2h(accO[j][0]*ir0);
        attb[base +   D_ ] = f2h(accO[j][1]*ir1);
        attb[base + 2*D_ ] = f2h(accO[j][2]*ir2);
        attb[base + 3*D_ ] = f2h(accO[j][3]*ir3);
    }
}

extern "C" void kernel_launch(void* const* d_in, const int* in_sizes, int n_in,
                              void* d_out, int out_size, void* d_ws, size_t ws_size,
                              hipStream_t stream)
{
    const float* x  = (const float*)d_in[0];
    const float* Wq = (const float*)d_in[1];
    const float* bq = (const float*)d_in[2];
    const float* Wk = (const float*)d_in[3];
    const float* bk = (const float*)d_in[4];
    const float* Wv = (const float*)d_in[5];
    const float* bv = (const float*)d_in[6];
    const float* Wo = (const float*)d_in[7];
    const float* bo = (const float*)d_in[8];
    const int* mask = (const int*)d_in[9];
    float* out = (float*)d_out;

    // workspace (72 MiB): all fp16
    unsigned short* qp  = (unsigned short*)d_ws;                 // 16 MiB
    unsigned short* kp  = qp  + (size_t)8*1024*1024;             // 16 MiB
    unsigned short* vtp = kp  + (size_t)8*1024*1024;             // 16 MiB [bh][d][t]
    unsigned short* xb  = vtp + (size_t)8*1024*1024;             // 16 MiB
    unsigned short* wt  = xb  + (size_t)8*1024*1024;             // 6 MiB
    unsigned short* wot = wt  + (size_t)3*1024*1024;             // 2 MiB
    unsigned short* attb = xb;   // alias: xb dead after gemm_qkvh

    prep_all  <<<3072, 256, 0, stream>>>(x, Wq, Wk, Wv, Wo, xb, wt, wot);
    gemm_qkvh <<<dim3(64,24), 256, 0, stream>>>(xb, wt, bq, bk, bv, qp, kp, vtp);
    attn_mfma <<<1024, 512, 0, stream>>>(qp, kp, vtp, attb, mask);
    gemm_o    <<<dim3(64,8), 256, 0, stream>>>(attb, wot, bo, out);
}

// Round 24
// 178.052 us; speedup vs baseline: 1.0701x; 1.0095x over previous
//
#include <hip/hip_runtime.h>
#include <hip/hip_bf16.h>
#include <math.h>

#define B_  4
#define T_  2048
#define D_  1024
#define H_  16
#define HD_ 64
#define M_  8192   // B_*T_

typedef __attribute__((ext_vector_type(8))) _Float16 f16x8;
typedef __attribute__((ext_vector_type(2))) __fp16  h16x2;
typedef __attribute__((ext_vector_type(4))) float   f32x4;

static __device__ __forceinline__ unsigned short f2h(float f){
    union { _Float16 h; unsigned short u; } cv; cv.h = (_Float16)f; return cv.u;
}
static __device__ __forceinline__ unsigned int pkh2(float a, float b){
    union { h16x2 h; unsigned int u; } cv;
    cv.h = __builtin_amdgcn_cvt_pkrtz(a, b);
    return cv.u;
}
static __device__ __forceinline__ void gload_lds16(const void* g, void* l){
    __builtin_amdgcn_global_load_lds(
        (const __attribute__((address_space(1))) unsigned int*)g,
        (__attribute__((address_space(3))) unsigned int*)l, 16, 0, 0);
}

union U16x16 { unsigned short us[16]; uint4 q[2]; };
union U16x4  { unsigned short us[4];  uint2 q;    };

// ---------------------------------------------------------------------------
// prep_all: one kernel, 3072 blocks (x->fp16; Wqkv/Wo transposed fp16).
// ---------------------------------------------------------------------------
__global__ __launch_bounds__(256) void prep_all(
    const float* __restrict__ x,
    const float* __restrict__ Wq, const float* __restrict__ Wk,
    const float* __restrict__ Wv, const float* __restrict__ Wo,
    unsigned short* __restrict__ xb, unsigned short* __restrict__ wt,
    unsigned short* __restrict__ wot)
{
    const int bid = blockIdx.x;
    const int t = threadIdx.x;

    if (bid < 2048){
        const size_t i = ((size_t)bid*256 + t)*16;
        U16x16 u;
#pragma unroll
        for (int j=0;j<16;j+=4){
            float4 f = *(const float4*)(x+i+j);
            u.us[j+0]=f2h(f.x); u.us[j+1]=f2h(f.y);
            u.us[j+2]=f2h(f.z); u.us[j+3]=f2h(f.w);
        }
        *(uint4*)(xb+i)   = u.q[0];
        *(uint4*)(xb+i+8) = u.q[1];
        return;
    }

    __shared__ float Tt[64][68];
    const int r = t >> 2, c4 = (t & 3) * 16;
    const int er = t >> 2, dk = (t & 3) * 16;

    if (bid < 2816){
        const int lb = bid - 2048;
        const int dt = lb & 15;
        const int zh = lb >> 4;
        const int z = zh >> 4, h = zh & 15;
        const float* src = ((z==0)?Wq:(z==1)?Wk:Wv) + (size_t)h*1024*64;
        const float* sp = src + (size_t)(dt*64 + r)*64 + c4;
        float4 v0=*(const float4*)(sp+0), v1=*(const float4*)(sp+4);
        float4 v2=*(const float4*)(sp+8), v3=*(const float4*)(sp+12);
        *(float4*)&Tt[r][c4+ 0]=v0; *(float4*)&Tt[r][c4+ 4]=v1;
        *(float4*)&Tt[r][c4+ 8]=v2; *(float4*)&Tt[r][c4+12]=v3;
        __syncthreads();
        U16x16 u;
#pragma unroll
        for (int j=0;j<16;j++) u.us[j] = f2h(Tt[dk+j][er]);
        unsigned short* dst = wt + (size_t)(z*1024 + h*64 + er)*1024 + dt*64 + dk;
        *(uint4*)(dst)   = u.q[0];
        *(uint4*)(dst+8) = u.q[1];
    } else {
        const int lb = bid - 2816;
        const int kt = lb & 15, nt = lb >> 4;
        const float* sp = Wo + (size_t)(kt*64 + r)*1024 + nt*64 + c4;
        float4 v0=*(const float4*)(sp+0), v1=*(const float4*)(sp+4);
        float4 v2=*(const float4*)(sp+8), v3=*(const float4*)(sp+12);
        *(float4*)&Tt[r][c4+ 0]=v0; *(float4*)&Tt[r][c4+ 4]=v1;
        *(float4*)&Tt[r][c4+ 8]=v2; *(float4*)&Tt[r][c4+12]=v3;
        __syncthreads();
        U16x16 u;
#pragma unroll
        for (int j=0;j<16;j++) u.us[j] = f2h(Tt[dk+j][er]);
        unsigned short* dst = wot + (size_t)(nt*64 + er)*1024 + kt*64 + dk;
        *(uint4*)(dst)   = u.q[0];
        *(uint4*)(dst+8) = u.q[1];
    }
}

// ---------------------------------------------------------------------------
// gemm_qkvh: unchanged (q scale folds 8*log2(e)).
// ---------------------------------------------------------------------------
__global__ __launch_bounds__(256) void gemm_qkvh(
    const unsigned short* __restrict__ xb, const unsigned short* __restrict__ wt,
    const float* __restrict__ bqv, const float* __restrict__ bkv,
    const float* __restrict__ bvv,
    unsigned short* __restrict__ qp, unsigned short* __restrict__ kp,
    unsigned short* __restrict__ vtp)
{
    const int m0 = blockIdx.x * 128;
    const int n0 = blockIdx.y * 128;
    const int tid = threadIdx.x;
    const int lane = tid & 63, w = tid >> 6;
    const int wr = w >> 1, wc = w & 1;
    const int fla = lane & 15, flb = lane >> 4;

    __shared__ unsigned short As[128*32];
    __shared__ unsigned short Bs[128*32];

    f32x4 acc[4][4];
#pragma unroll
    for (int i=0;i<4;i++)
#pragma unroll
        for (int j=0;j<4;j++) acc[i][j] = (f32x4){0.f,0.f,0.f,0.f};

    const int srow0 = w*32 + (lane>>2);
    const int srow1 = srow0 + 16;
    const int spc   = lane & 3;
    const size_t ga0 = (size_t)(m0+srow0)*1024 + (size_t)((spc ^ ((srow0>>1)&3))*8);
    const size_t ga1 = (size_t)(m0+srow1)*1024 + (size_t)((spc ^ ((srow1>>1)&3))*8);
    const size_t gb0 = (size_t)(n0+srow0)*1024 + (size_t)((spc ^ ((srow0>>1)&3))*8);
    const size_t gb1 = (size_t)(n0+srow1)*1024 + (size_t)((spc ^ ((srow1>>1)&3))*8);
    const int ldso0 = w*1024;          // shorts
    const int ldso1 = w*1024 + 512;
    const int pchunk = (flb ^ ((fla>>1)&3)) * 8;

    for (int ks = 0; ks < 32; ++ks){
        const size_t k0 = (size_t)ks*32;
        __syncthreads();   // prev chunk's fragment reads complete
        gload_lds16(xb + ga0 + k0, As + ldso0);
        gload_lds16(xb + ga1 + k0, As + ldso1);
        gload_lds16(wt + gb0 + k0, Bs + ldso0);
        gload_lds16(wt + gb1 + k0, Bs + ldso1);
        __syncthreads();   // vmcnt(0) drained at barrier

        f16x8 af[4], bfr[4];
#pragma unroll
        for (int mf=0; mf<4; ++mf)
            af[mf] = *(const f16x8*)&As[(wr*64+mf*16+fla)*32 + pchunk];
#pragma unroll
        for (int nf=0; nf<4; ++nf)
            bfr[nf] = *(const f16x8*)&Bs[(wc*64+nf*16+fla)*32 + pchunk];
#pragma unroll
        for (int mf=0; mf<4; ++mf)
#pragma unroll
            for (int nf=0; nf<4; ++nf)
                acc[mf][nf] = __builtin_amdgcn_mfma_f32_16x16x32_f16(
                                  af[mf], bfr[nf], acc[mf][nf], 0, 0, 0);
    }

#pragma unroll
    for (int nf=0; nf<4; ++nf){
        const int c = n0 + wc*64 + nf*16 + fla;
        const int z = c >> 10, rem = c & 1023;
        const int h = rem >> 6, e = rem & 63;
        if (z < 2){
            const float bias = ((z==0)?bqv:bkv)[rem];
            const float scl  = (z==0) ? 11.541560327111708f   // 8*log2(e)
                                      : 1.0f;
            unsigned short* op = (z==0)?qp:kp;
#pragma unroll
            for (int mf=0; mf<4; ++mf){
#pragma unroll
                for (int ri=0; ri<4; ++ri){
                    const int m = m0 + wr*64 + mf*16 + flb*4 + ri;
                    const int b = m >> 11, t = m & (T_-1);
                    op[((size_t)(b*H_ + h)*T_ + t)*HD_ + e] =
                        f2h((acc[mf][nf][ri] + bias) * scl);
                }
            }
        } else {
            const float bias = bvv[rem];
#pragma unroll
            for (int mf=0; mf<4; ++mf){
                const int m = m0 + wr*64 + mf*16 + flb*4;   // 4 consecutive t
                const int b = m >> 11, t = m & (T_-1);
                U16x4 u;
#pragma unroll
                for (int ri=0; ri<4; ++ri)
                    u.us[ri] = f2h(acc[mf][nf][ri] + bias);
                *(uint2*)(vtp + ((size_t)(b*H_ + h)*HD_ + e)*T_ + t) = u.q;
            }
        }
    }
}

// ---------------------------------------------------------------------------
// gemm_o: out = att(fp16) @ wot(fp16) + bo. (unchanged)
// ---------------------------------------------------------------------------
__global__ __launch_bounds__(256) void gemm_o(
    const unsigned short* __restrict__ attb, const unsigned short* __restrict__ wot,
    const float* __restrict__ bo, float* __restrict__ out)
{
    const int m0 = blockIdx.x * 128;
    const int n0 = blockIdx.y * 128;
    const int tid = threadIdx.x;
    const int lane = tid & 63, w = tid >> 6;
    const int wr = w >> 1, wc = w & 1;
    const int fla = lane & 15, flb = lane >> 4;

    __shared__ unsigned short As[4096];
    __shared__ unsigned short Bs[4096];

    f32x4 acc[4][4];
#pragma unroll
    for (int i=0;i<4;i++)
#pragma unroll
        for (int j=0;j<4;j++) acc[i][j] = (f32x4){0.f,0.f,0.f,0.f};

    const int srow0 = w*32 + (lane>>2);
    const int srow1 = srow0 + 16;
    const int spc   = lane & 3;
    const size_t ga0 = (size_t)(m0+srow0)*1024 + (size_t)((spc ^ ((srow0>>1)&3))*8);
    const size_t ga1 = (size_t)(m0+srow1)*1024 + (size_t)((spc ^ ((srow1>>1)&3))*8);
    const size_t gb0 = (size_t)(n0+srow0)*1024 + (size_t)((spc ^ ((srow0>>1)&3))*8);
    const size_t gb1 = (size_t)(n0+srow1)*1024 + (size_t)((spc ^ ((srow1>>1)&3))*8);
    const int ldso0 = w*1024;
    const int ldso1 = w*1024 + 512;
    const int pchunk = (flb ^ ((fla>>1)&3)) * 8;

    for (int ks = 0; ks < 32; ++ks){
        const size_t k0 = (size_t)ks*32;
        __syncthreads();
        gload_lds16(attb + ga0 + k0, As + ldso0);
        gload_lds16(attb + ga1 + k0, As + ldso1);
        gload_lds16(wot  + gb0 + k0, Bs + ldso0);
        gload_lds16(wot  + gb1 + k0, Bs + ldso1);
        __syncthreads();

        f16x8 af[4], bfr[4];
#pragma unroll
        for (int mf=0; mf<4; ++mf)
            af[mf] = *(const f16x8*)&As[(wr*64+mf*16+fla)*32 + pchunk];
#pragma unroll
        for (int nf=0; nf<4; ++nf)
            bfr[nf] = *(const f16x8*)&Bs[(wc*64+nf*16+fla)*32 + pchunk];
#pragma unroll
        for (int mf=0; mf<4; ++mf)
#pragma unroll
            for (int nf=0; nf<4; ++nf)
                acc[mf][nf] = __builtin_amdgcn_mfma_f32_16x16x32_f16(
                                  af[mf], bfr[nf], acc[mf][nf], 0, 0, 0);
    }

#pragma unroll
    for (int nf=0; nf<4; ++nf){
        const int n = n0 + wc*64 + nf*16 + fla;
        const float bias = bo[n];
#pragma unroll
        for (int mf=0; mf<4; ++mf){
#pragma unroll
            for (int ri=0; ri<4; ++ri){
                const int m = m0 + wr*64 + mf*16 + flb*4 + ri;
                out[(size_t)m*D_ + n] = acc[mf][nf][ri] + bias;
            }
        }
    }
}

// ---------------------------------------------------------------------------
// MFMA flash attention (R22 structure) + s_setprio around MFMA clusters +
// max3-fusable row-max chain.
// ---------------------------------------------------------------------------
__global__ __launch_bounds__(512) void attn_mfma(
    const unsigned short* __restrict__ qp, const unsigned short* __restrict__ kp,
    const unsigned short* __restrict__ vtp, unsigned short* __restrict__ attb,
    const int* __restrict__ maskp)
{
    const int bid = blockIdx.x;
    const int qb2 = 15 - (bid >> 6);   // big q-blocks first (128 rows each)
    const int bh  = bid & 63;
    const int b   = bh >> 4, h = bh & 15;
    const int tid = threadIdx.x;
    const int lane = tid & 63, w = tid >> 6;      // w = 0..7
    const int l16 = lane & 15, h16 = lane >> 4;
    const int domask = maskp[0];

    __shared__ unsigned short KPS[16384];        // K (16KB), then P (32KB)
    __shared__ unsigned short VtS[4][64][32];    // [key-chunk][d][key%32]

    const int qrow = qb2*128 + w*16 + l16;       // this lane's softmax row
    const size_t qoff = ((size_t)bh*T_ + qrow)*HD_ + 8*h16;
    const f16x8 q0 = *(const f16x8*)(qp + qoff);
    const f16x8 q1 = *(const f16x8*)(qp + qoff + 32);

    f32x4 accO[4];
#pragma unroll
    for (int j=0;j<4;j++) accO[j] = (f32x4){0.f,0.f,0.f,0.f};
    float m_run = -INFINITY, lpart = 0.f;

    // staging geometry (512 threads, 2 uint4 each per operand)
    const int kr  = tid >> 2;          // 0..127 key row (K)
    const int kq  = tid & 3;           // d-16-segment
    const int kh  = kq >> 1;           // d-half
    const int ksb = (kq & 1) * 2;      // first logical sub-block
    const int fk  = (kr >> 1) & 3;
    const int vr  = tid >> 3;          // 0..63 d row (V)
    const int vs8 = tid & 7;           // key-16-segment
    const int vq  = vs8 >> 1;          // key quarter
    const int vsb = (vs8 & 1) * 2;
    const int fv  = (vr >> 1) & 3;

    // fragment-read swizzle (all fragment rows == l16 mod 16)
    const int off = (h16 ^ ((l16>>1)&3)) * 8;
    const int psw = (l16>>1)&3;        // P-row swizzle key (row = w*16+l16)

    const size_t kbase = (size_t)bh*T_*HD_;
    const size_t vbase = (size_t)bh*HD_*T_;

    const int nchunks = domask ? (qb2+1) : 16;
    for (int ci = 0; ci < nchunks; ++ci){
        const int kb = ci << 7;
        const unsigned short* ksrc = kp + kbase + (size_t)(kb+kr)*HD_ + kq*16;
        uint4 ka0=*(const uint4*)(ksrc), ka1=*(const uint4*)(ksrc+8);
        const unsigned short* vsrc = vtp + vbase + (size_t)vr*T_ + kb + vs8*16;
        uint4 va0=*(const uint4*)(vsrc), va1=*(const uint4*)(vsrc+8);
        __syncthreads();   // prev chunk's PV reads (KPS=P rows, VtS) complete
        *(uint4*)&KPS[kh*4096 + kr*32 + (((ksb  )^fk)*8)] = ka0;
        *(uint4*)&KPS[kh*4096 + kr*32 + (((ksb+1)^fk)*8)] = ka1;
        *(uint4*)&VtS[vq][vr][((vsb  )^fv)*8] = va0;
        *(uint4*)&VtS[vq][vr][((vsb+1)^fv)*8] = va1;
        __syncthreads();

        // S^T = K Q : s[j][reg] = S[qrow][key = kb + 16j + 4*h16 + reg]
        f32x4 s[8];
        __builtin_amdgcn_s_setprio(1);
#pragma unroll
        for (int j=0;j<8;j++){
            const f16x8 k0 = *(const f16x8*)&KPS[       (j*16+l16)*32 + off];
            const f16x8 k1 = *(const f16x8*)&KPS[4096 + (j*16+l16)*32 + off];
            f32x4 a = (f32x4){0.f,0.f,0.f,0.f};
            a = __builtin_amdgcn_mfma_f32_16x16x32_f16(k0, q0, a, 0,0,0);
            a = __builtin_amdgcn_mfma_f32_16x16x32_f16(k1, q1, a, 0,0,0);
            s[j] = a;
        }
        __builtin_amdgcn_s_setprio(0);
        if (domask && ci == nchunks-1){
#pragma unroll
            for (int j=0;j<8;j++)
#pragma unroll
                for (int reg=0;reg<4;reg++)
                    if (kb + j*16 + 4*h16 + reg > qrow)
                        s[j][reg] = -INFINITY;
        }

        // row max: max3-fusable chain (16 ops) + 2 cross-lane
        float mloc = -INFINITY;
#pragma unroll
        for (int j=0;j<8;j++){
            mloc = fmaxf(fmaxf(mloc, s[j][0]), s[j][1]);   // -> v_max3
            mloc = fmaxf(fmaxf(mloc, s[j][2]), s[j][3]);   // -> v_max3
        }
        mloc = fmaxf(mloc, __shfl_xor(mloc,16));
        mloc = fmaxf(mloc, __shfl_xor(mloc,32));

        // defer-max: skip rescale when growth <= 8 (log2 units -> P <= 256)
        const bool small = (mloc <= m_run + 8.f);
        if (!__all(small)){
            const float mnew = fmaxf(m_run, mloc);
            const float scl  = exp2f(m_run - mnew);   // 0 on first chunk
            m_run = mnew;
            lpart *= scl;
            const float sr0 = __shfl(scl, 4*h16+0);
            const float sr1 = __shfl(scl, 4*h16+1);
            const float sr2 = __shfl(scl, 4*h16+2);
            const float sr3 = __shfl(scl, 4*h16+3);
#pragma unroll
            for (int j=0;j<4;j++){
                accO[j][0] *= sr0; accO[j][1] *= sr1;
                accO[j][2] *= sr2; accO[j][3] *= sr3;
            }
        }

        __syncthreads();   // all K reads done before P overwrites KPS

        // P = exp2(S - m); pack consecutive-key pairs; b32 swizzled stores
        const int prow = w*16 + l16;               // 0..127
        float ps = 0.f;
#pragma unroll
        for (int j=0;j<8;j++){
            const float p0 = exp2f(s[j][0]-m_run);
            const float p1 = exp2f(s[j][1]-m_run);
            const float p2 = exp2f(s[j][2]-m_run);
            const float p3 = exp2f(s[j][3]-m_run);
            ps += (p0+p1)+(p2+p3);
            const unsigned int u01 = pkh2(p0,p1);
            const unsigned int u23 = pkh2(p2,p3);
            const int sb = 2*(j&1) + (h16>>1);
            const int so = ((sb ^ psw)<<3) + 4*(h16&1);
            *(unsigned int*)&KPS[(j>>1)*4096 + prow*32 + so]     = u01;
            *(unsigned int*)&KPS[(j>>1)*4096 + prow*32 + so + 2] = u23;
        }
        lpart += ps;

        // O += P V (P rows wave-private; same-wave RAW via lgkmcnt)
        __builtin_amdgcn_s_setprio(1);
#pragma unroll
        for (int kc=0;kc<4;kc++){
            const f16x8 pa = *(const f16x8*)&KPS[kc*4096 + (w*16+l16)*32 + off];
#pragma unroll
            for (int j=0;j<4;j++){
                const f16x8 vb_ = *(const f16x8*)&VtS[kc][j*16+l16][off];
                accO[j] = __builtin_amdgcn_mfma_f32_16x16x32_f16(pa, vb_, accO[j], 0,0,0);
            }
        }
        __builtin_amdgcn_s_setprio(0);
    }

    // final denominator: reduce across the 4 lanes sharing this q-row,
    // then redistribute to accO's row keying (4*h16+reg)
    float l = lpart;
    l += __shfl_xor(l,16); l += __shfl_xor(l,32);
    const float inv = 1.0f / l;
    const float ir0 = __shfl(inv, 4*h16+0);
    const float ir1 = __shfl(inv, 4*h16+1);
    const float ir2 = __shfl(inv, 4*h16+2);
    const float ir3 = __shfl(inv, 4*h16+3);
    const int t0 = qb2*128 + w*16 + 4*h16;
#pragma unroll
    for (int j=0;j<4;j++){
        const size_t base = ((size_t)b*T_ + t0)*D_ + h*HD_ + j*16 + l16;
        attb[base        ] = f2h(accO[j][0]*ir0);
        attb[base +   D_ ] = f2h(accO[j][1]*ir1);
        attb[base + 2*D_ ] = f2h(accO[j][2]*ir2);
        attb[base + 3*D_ ] = f2h(accO[j][3]*ir3);
    }
}

extern "C" void kernel_launch(void* const* d_in, const int* in_sizes, int n_in,
                              void* d_out, int out_size, void* d_ws, size_t ws_size,
                              hipStream_t stream)
{
    const float* x  = (const float*)d_in[0];
    const float* Wq = (const float*)d_in[1];
    const float* bq = (const float*)d_in[2];
    const float* Wk = (const float*)d_in[3];
    const float* bk = (const float*)d_in[4];
    const float* Wv = (const float*)d_in[5];
    const float* bv = (const float*)d_in[6];
    const float* Wo = (const float*)d_in[7];
    const float* bo = (const float*)d_in[8];
    const int* mask = (const int*)d_in[9];
    float* out = (float*)d_out;

    // workspace (72 MiB): all fp16
    unsigned short* qp  = (unsigned short*)d_ws;                 // 16 MiB
    unsigned short* kp  = qp  + (size_t)8*1024*1024;             // 16 MiB
    unsigned short* vtp = kp  + (size_t)8*1024*1024;             // 16 MiB [bh][d][t]
    unsigned short* xb  = vtp + (size_t)8*1024*1024;             // 16 MiB
    unsigned short* wt  = xb  + (size_t)8*1024*1024;             // 6 MiB
    unsigned short* wot = wt  + (size_t)3*1024*1024;             // 2 MiB
    unsigned short* attb = xb;   // alias: xb dead after gemm_qkvh

    prep_all  <<<3072, 256, 0, stream>>>(x, Wq, Wk, Wv, Wo, xb, wt, wot);
    gemm_qkvh <<<dim3(64,24), 256, 0, stream>>>(xb, wt, bq, bk, bv, qp, kp, vtp);
    attn_mfma <<<1024, 512, 0, stream>>>(qp, kp, vtp, attb, mask);
    gemm_o    <<<dim3(64,8), 256, 0, stream>>>(attb, wot, bo, out);
}